// Round 1
// baseline (773.996 us; speedup 1.0000x reference)
//
#include <hip/hip_runtime.h>

// MixerBlock: B=8, T=2048, E=1024, H=16, HD=64, DFF=4096, DC=4
// Pipeline (all on `stream`):
//   prep: transpose+cast weights to bf16 (N x K) in ws
//   K1: LN1(x) -> h_bf16
//   K2: GEMM1 h @ Wp -> p_bf16 (+b_proj)
//   K3/K4: chunked causal-decay scan -> mixed_bf16 (+mix_b, mix_w)
//   K5: GEMM2 mixed @ out_w + out_b + x -> x2 (f32, stored in d_out)
//   K6: LN2(x2) -> g_bf16
//   K7: GEMM3 g @ ff_w1 + ff_b1 -> gelu -> u_bf16
//   K8: GEMM4 u @ ff_w2 + ff_b2 + x2 -> d_out (f32)
// Workspace usage ~181 MiB (see layout in kernel_launch).

#define TT 2048
#define EE 1024
#define HHD 64
#define MROWS 16384
#define SC_C 32
#define SC_L 64

typedef __bf16 bf16x8 __attribute__((ext_vector_type(8)));
typedef float f32x4 __attribute__((ext_vector_type(4)));
typedef unsigned short u16;
typedef unsigned int u32;

__device__ __forceinline__ u16 f2bf(float f) {
  u32 u = __builtin_bit_cast(u32, f);
  u += 0x7FFFu + ((u >> 16) & 1u);      // round-to-nearest-even
  return (u16)(u >> 16);
}
__device__ __forceinline__ float bf2f(u16 s) {
  u32 u = ((u32)s) << 16;
  return __builtin_bit_cast(float, u);
}
__device__ __forceinline__ float gelu_f(float x) {
  // tanh approximation (matches jax.nn.gelu approximate=True)
  float u = 0.7978845608028654f * x * (1.0f + 0.044715f * x * x);
  float e = __expf(2.0f * u);
  float t = 1.0f - 2.0f / (e + 1.0f);   // tanh(u)
  return 0.5f * x * (1.0f + t);
}
__device__ __forceinline__ void gload_lds16(const void* g, void* l) {
  __builtin_amdgcn_global_load_lds(
      (const __attribute__((address_space(1))) u32*)g,
      (__attribute__((address_space(3))) u32*)l, 16, 0, 0);
}

// ---------------- weight transpose + cast: src (R x C) f32 -> dst (C x R) bf16, batched
__global__ __launch_bounds__(256) void transpose_to_bf16(
    const float* __restrict__ src, u16* __restrict__ dst, int R, int C,
    long sbs, long dbs) {
  __shared__ float tile[32][33];
  src += (long)blockIdx.z * sbs;
  dst += (long)blockIdx.z * dbs;
  int c0 = blockIdx.x * 32, r0 = blockIdx.y * 32;
  int tx = threadIdx.x, ty = threadIdx.y;
#pragma unroll
  for (int i = 0; i < 4; i++)
    tile[ty + i * 8][tx] = src[(long)(r0 + ty + i * 8) * C + c0 + tx];
  __syncthreads();
#pragma unroll
  for (int i = 0; i < 4; i++)
    dst[(long)(c0 + ty + i * 8) * R + r0 + tx] = f2bf(tile[tx][ty + i * 8]);
}

// ---------------- LayerNorm over E=1024, one row per block (256 thr, 4 elem/thr)
__global__ __launch_bounds__(256) void ln_to_bf16(
    const float* __restrict__ x, const float* __restrict__ gam,
    const float* __restrict__ bet, u16* __restrict__ y) {
  int row = blockIdx.x;
  int tid = threadIdx.x;
  float4 v = ((const float4*)x)[row * 256 + tid];
  float s = v.x + v.y + v.z + v.w;
  float s2 = v.x * v.x + v.y * v.y + v.z * v.z + v.w * v.w;
#pragma unroll
  for (int off = 1; off < 64; off <<= 1) {
    s += __shfl_xor(s, off);
    s2 += __shfl_xor(s2, off);
  }
  __shared__ float red[8];
  int w = tid >> 6;
  if ((tid & 63) == 0) { red[w] = s; red[4 + w] = s2; }
  __syncthreads();
  s = red[0] + red[1] + red[2] + red[3];
  s2 = red[4] + red[5] + red[6] + red[7];
  float mu = s * (1.0f / 1024.0f);
  float var = s2 * (1.0f / 1024.0f) - mu * mu;
  float rstd = rsqrtf(var + 1e-5f);
  int e0 = tid * 4;
  ushort4 o;
  o.x = f2bf((v.x - mu) * rstd * gam[e0 + 0] + bet[e0 + 0]);
  o.y = f2bf((v.y - mu) * rstd * gam[e0 + 1] + bet[e0 + 1]);
  o.z = f2bf((v.z - mu) * rstd * gam[e0 + 2] + bet[e0 + 2]);
  o.w = f2bf((v.w - mu) * rstd * gam[e0 + 3] + bet[e0 + 3]);
  ((ushort4*)y)[row * 256 + tid] = o;
}

// ---------------- bf16 GEMM, 128x128 tile, BK=32, 4 waves (2x2), m97 structure.
// A: (M x K) bf16 row-major. Bt: (N x K) bf16 row-major (weights pre-transposed).
// EPI 0: out bf16 = acc+bias ; 1: out f32 = acc+bias+res ; 2: out bf16 = gelu(acc+bias)
template <int EPI>
__global__ __launch_bounds__(256) void gemm_bf16(
    const u16* __restrict__ A, const u16* __restrict__ Bt,
    const float* __restrict__ bias, const float* res, void* outp,
    int M, int N, int K) {
  __shared__ bf16x8 lds8[1024];  // 16 KiB: As bytes [0,8192), Bs [8192,16384)
  u16* As = (u16*)lds8;
  u16* Bs = As + 4096;
  const int tid = threadIdx.x;
  const int w = tid >> 6, lane = tid & 63;
  const int wm = w >> 1, wn = w & 1;
  const int l15 = lane & 15, lk = lane >> 4;
  const int m0 = blockIdx.y * 128, n0 = blockIdx.x * 128;
  const int srow = lane >> 2;      // staging: row within 16-row group
  const int sk = (lane & 3) * 8;   // staging: k-element offset (8 bf16 = 16B)

  f32x4 acc[4][4];
  const f32x4 z = {0.f, 0.f, 0.f, 0.f};
#pragma unroll
  for (int mi = 0; mi < 4; mi++)
#pragma unroll
    for (int ni = 0; ni < 4; ni++) acc[mi][ni] = z;

  const bf16x8* As8 = (const bf16x8*)As;
  const bf16x8* Bs8 = (const bf16x8*)Bs;

  for (int kt = 0; kt < K; kt += 32) {
#pragma unroll
    for (int j = 0; j < 2; j++) {
      int rgrp = w * 2 + j;                 // wave-uniform
      int row = rgrp * 16 + srow;
      gload_lds16(A + (size_t)(m0 + row) * K + kt + sk, As + rgrp * 512);
      gload_lds16(Bt + (size_t)(n0 + row) * K + kt + sk, Bs + rgrp * 512);
    }
    __syncthreads();  // drains vmcnt before barrier -> LDS tiles ready
    bf16x8 af[4], bfv[4];
#pragma unroll
    for (int mi = 0; mi < 4; mi++) af[mi] = As8[(wm * 64 + mi * 16 + l15) * 4 + lk];
#pragma unroll
    for (int ni = 0; ni < 4; ni++) bfv[ni] = Bs8[(wn * 64 + ni * 16 + l15) * 4 + lk];
#pragma unroll
    for (int mi = 0; mi < 4; mi++)
#pragma unroll
      for (int ni = 0; ni < 4; ni++)
        acc[mi][ni] = __builtin_amdgcn_mfma_f32_16x16x32_bf16(af[mi], bfv[ni],
                                                              acc[mi][ni], 0, 0, 0);
    __syncthreads();
  }

#pragma unroll
  for (int mi = 0; mi < 4; mi++) {
#pragma unroll
    for (int ni = 0; ni < 4; ni++) {
      int n = n0 + wn * 64 + ni * 16 + l15;   // C/D: col = lane&15 (m89-verified)
      float bv = bias[n];
#pragma unroll
      for (int r = 0; r < 4; r++) {
        int m = m0 + wm * 64 + mi * 16 + lk * 4 + r;  // row = (lane>>4)*4 + reg
        size_t idx = (size_t)m * N + n;
        float v = acc[mi][ni][r] + bv;
        if (EPI == 0) {
          ((u16*)outp)[idx] = f2bf(v);
        } else if (EPI == 1) {
          ((float*)outp)[idx] = v + res[idx];
        } else {
          ((u16*)outp)[idx] = f2bf(gelu_f(v));
        }
      }
    }
  }
}

// ---------------- causal decay mixing as a chunked linear scan.
// S[s] = r*S[s-1] + q[s], r = clip(decay,0.9,1)^(1/4)
// col heads (h<8): q = p,          out = mix_w[h,s]*S + mix_b[h,s]
// row heads (h>=8): q = mix_w[h,t]*p, out = S + mix_b[h,s]
__global__ __launch_bounds__(64) void scan_carry(
    const u16* __restrict__ p, const float* __restrict__ mix_w,
    const float* __restrict__ decay, float* __restrict__ carry) {
  int blk = blockIdx.x;
  int c = blk & 31, h = (blk >> 5) & 15, b = blk >> 9;
  int f = threadIdx.x;
  float d = fminf(fmaxf(decay[h], 0.9f), 1.0f);
  float r = powf(d, 0.25f);
  size_t base = ((size_t)b * TT + c * SC_L) * EE + h * HHD + f;
  const float* mw = mix_w + h * TT + c * SC_L;
  bool isRow = (h >= 8);
  float S = 0.f;
#pragma unroll 4
  for (int t = 0; t < SC_L; t++) {
    float pv = bf2f(p[base + (size_t)t * EE]);
    float q = isRow ? mw[t] * pv : pv;
    S = r * S + q;
  }
  carry[blk * 64 + f] = S;
}

__global__ __launch_bounds__(64) void scan_apply(
    const u16* __restrict__ p, const float* __restrict__ mix_w,
    const float* __restrict__ mix_b, const float* __restrict__ decay,
    const float* __restrict__ carry, u16* __restrict__ mixed) {
  int blk = blockIdx.x;
  int c = blk & 31, h = (blk >> 5) & 15, b = blk >> 9;
  int f = threadIdx.x;
  float d = fminf(fmaxf(decay[h], 0.9f), 1.0f);
  float r = powf(d, 0.25f);
  float rl = powf(r, (float)SC_L);
  int cb = blk - c;
  float S = 0.f;
  for (int cc = 0; cc < c; cc++) S = rl * S + carry[(cb + cc) * 64 + f];
  size_t base = ((size_t)b * TT + c * SC_L) * EE + h * HHD + f;
  const float* mw = mix_w + h * TT + c * SC_L;
  const float* mb = mix_b + h * TT + c * SC_L;
  bool isRow = (h >= 8);
  for (int t = 0; t < SC_L; t++) {
    float pv = bf2f(p[base + (size_t)t * EE]);
    float q = isRow ? mw[t] * pv : pv;
    S = r * S + q;
    float val = (isRow ? S : mw[t] * S) + mb[t];
    mixed[base + (size_t)t * EE] = f2bf(val);
  }
}

extern "C" void kernel_launch(void* const* d_in, const int* in_sizes, int n_in,
                              void* d_out, int out_size, void* d_ws, size_t ws_size,
                              hipStream_t stream) {
  const float* x = (const float*)d_in[0];
  const float* w_proj = (const float*)d_in[1];
  const float* b_proj = (const float*)d_in[2];
  const float* mix_w = (const float*)d_in[3];
  const float* mix_b = (const float*)d_in[4];
  const float* decay = (const float*)d_in[5];
  const float* out_w = (const float*)d_in[6];
  const float* out_b = (const float*)d_in[7];
  const float* ln1_g = (const float*)d_in[8];
  const float* ln1_b = (const float*)d_in[9];
  const float* ln2_g = (const float*)d_in[10];
  const float* ln2_b = (const float*)d_in[11];
  const float* ff_w1 = (const float*)d_in[12];
  const float* ff_b1 = (const float*)d_in[13];
  const float* ff_w2 = (const float*)d_in[14];
  const float* ff_b2 = (const float*)d_in[15];
  float* out = (float*)d_out;

  // ws layout (MiB): [0,2)Wp [2,4)Wo [4,12)W1 [12,20)W2 [20,52)mixed/g
  //                  [52,180)u  (h at 52, p at 84 — both dead before u written)
  //                  [180,181)carry.  Total ~181 MiB.
  char* ws = (char*)d_ws;
  const size_t MiB = 1ull << 20;
  u16* wWp = (u16*)(ws + 0 * MiB);
  u16* wWo = (u16*)(ws + 2 * MiB);
  u16* wW1 = (u16*)(ws + 4 * MiB);
  u16* wW2 = (u16*)(ws + 12 * MiB);
  u16* wMix = (u16*)(ws + 20 * MiB);
  u16* wH = (u16*)(ws + 52 * MiB);
  u16* wP = (u16*)(ws + 84 * MiB);
  u16* wU = (u16*)(ws + 52 * MiB);
  float* wCarry = (float*)(ws + 180 * MiB);

  dim3 tb(32, 8);
  // w_proj (H,E,HD): per-head (E x HD) -> (HD x E), head h at dst row h*64
  transpose_to_bf16<<<dim3(2, 32, 16), tb, 0, stream>>>(w_proj, wWp, 1024, 64,
                                                        65536L, 65536L);
  transpose_to_bf16<<<dim3(32, 32, 1), tb, 0, stream>>>(out_w, wWo, 1024, 1024, 0L, 0L);
  transpose_to_bf16<<<dim3(128, 32, 1), tb, 0, stream>>>(ff_w1, wW1, 1024, 4096, 0L, 0L);
  transpose_to_bf16<<<dim3(32, 128, 1), tb, 0, stream>>>(ff_w2, wW2, 4096, 1024, 0L, 0L);

  ln_to_bf16<<<dim3(MROWS), dim3(256), 0, stream>>>(x, ln1_g, ln1_b, wH);

  gemm_bf16<0><<<dim3(8, 128), dim3(256), 0, stream>>>(
      wH, wWp, b_proj, (const float*)nullptr, (void*)wP, MROWS, 1024, 1024);

  scan_carry<<<dim3(4096), dim3(64), 0, stream>>>(wP, mix_w, decay, wCarry);
  scan_apply<<<dim3(4096), dim3(64), 0, stream>>>(wP, mix_w, mix_b, decay, wCarry, wMix);

  gemm_bf16<1><<<dim3(8, 128), dim3(256), 0, stream>>>(
      wMix, wWo, out_b, x, (void*)out, MROWS, 1024, 1024);

  ln_to_bf16<<<dim3(MROWS), dim3(256), 0, stream>>>(out, ln2_g, ln2_b, wMix);

  gemm_bf16<2><<<dim3(32, 128), dim3(256), 0, stream>>>(
      wMix, wW1, ff_b1, (const float*)nullptr, (void*)wU, MROWS, 4096, 1024);

  gemm_bf16<1><<<dim3(8, 128), dim3(256), 0, stream>>>(
      wU, wW2, ff_b2, out, (void*)out, MROWS, 1024, 4096);
}

// Round 2
// 556.911 us; speedup vs baseline: 1.3898x; 1.3898x over previous
//
#include <hip/hip_runtime.h>

// MixerBlock: B=8, T=2048, E=1024, H=16, HD=64, DFF=4096, DC=4
// Pipeline (all on `stream`):
//   prep: transpose+cast weights to bf16 (N x K) in ws
//   K1: LN1(x) -> h_bf16
//   K2: GEMM1 h @ Wp -> p_bf16 (+b_proj)
//   K3/K4: chunked causal-decay scan -> mixed_bf16 (+mix_b, mix_w)
//   K5: GEMM2 mixed @ out_w + out_b + x -> x2 (f32, stored in d_out)
//   K6: LN2(x2) -> g_bf16
//   K7: GEMM3 g @ ff_w1 + ff_b1 -> gelu -> u_bf16
//   K8: GEMM4 u @ ff_w2 + ff_b2 + x2 -> d_out (f32)
// GEMM: 256x256 tile, BK=64, 8 waves (2Mx4N), double-buffered 128 KiB LDS,
//       2-phase pipeline (stage next || compute cur, one barrier per K-tile),
//       T1 XCD swizzle + T2 LDS slot-swizzle (both-sides) + T5 setprio.

#define TT 2048
#define EE 1024
#define HHD 64
#define MROWS 16384
#define SC_L 64

typedef __bf16 bf16x8 __attribute__((ext_vector_type(8)));
typedef float f32x4 __attribute__((ext_vector_type(4)));
typedef unsigned short u16;
typedef unsigned int u32;

__device__ __forceinline__ u16 f2bf(float f) {
  u32 u = __builtin_bit_cast(u32, f);
  u += 0x7FFFu + ((u >> 16) & 1u);      // round-to-nearest-even
  return (u16)(u >> 16);
}
__device__ __forceinline__ float bf2f(u16 s) {
  u32 u = ((u32)s) << 16;
  return __builtin_bit_cast(float, u);
}
__device__ __forceinline__ float gelu_f(float x) {
  // tanh approximation (matches jax.nn.gelu approximate=True)
  float u = 0.7978845608028654f * x * (1.0f + 0.044715f * x * x);
  float e = __expf(2.0f * u);
  float t = 1.0f - 2.0f / (e + 1.0f);   // tanh(u)
  return 0.5f * x * (1.0f + t);
}
__device__ __forceinline__ void gload_lds16(const void* g, void* l) {
  __builtin_amdgcn_global_load_lds(
      (const __attribute__((address_space(1))) u32*)g,
      (__attribute__((address_space(3))) u32*)l, 16, 0, 0);
}

// ---------------- weight transpose + cast: src (R x C) f32 -> dst (C x R) bf16, batched
__global__ __launch_bounds__(256) void transpose_to_bf16(
    const float* __restrict__ src, u16* __restrict__ dst, int R, int C,
    long sbs, long dbs) {
  __shared__ float tile[32][33];
  src += (long)blockIdx.z * sbs;
  dst += (long)blockIdx.z * dbs;
  int c0 = blockIdx.x * 32, r0 = blockIdx.y * 32;
  int tx = threadIdx.x, ty = threadIdx.y;
#pragma unroll
  for (int i = 0; i < 4; i++)
    tile[ty + i * 8][tx] = src[(long)(r0 + ty + i * 8) * C + c0 + tx];
  __syncthreads();
#pragma unroll
  for (int i = 0; i < 4; i++)
    dst[(long)(c0 + ty + i * 8) * R + r0 + tx] = f2bf(tile[tx][ty + i * 8]);
}

// ---------------- LayerNorm over E=1024, one row per block (256 thr, 4 elem/thr)
__global__ __launch_bounds__(256) void ln_to_bf16(
    const float* __restrict__ x, const float* __restrict__ gam,
    const float* __restrict__ bet, u16* __restrict__ y) {
  int row = blockIdx.x;
  int tid = threadIdx.x;
  float4 v = ((const float4*)x)[row * 256 + tid];
  float s = v.x + v.y + v.z + v.w;
  float s2 = v.x * v.x + v.y * v.y + v.z * v.z + v.w * v.w;
#pragma unroll
  for (int off = 1; off < 64; off <<= 1) {
    s += __shfl_xor(s, off);
    s2 += __shfl_xor(s2, off);
  }
  __shared__ float red[8];
  int w = tid >> 6;
  if ((tid & 63) == 0) { red[w] = s; red[4 + w] = s2; }
  __syncthreads();
  s = red[0] + red[1] + red[2] + red[3];
  s2 = red[4] + red[5] + red[6] + red[7];
  float mu = s * (1.0f / 1024.0f);
  float var = s2 * (1.0f / 1024.0f) - mu * mu;
  float rstd = rsqrtf(var + 1e-5f);
  int e0 = tid * 4;
  ushort4 o;
  o.x = f2bf((v.x - mu) * rstd * gam[e0 + 0] + bet[e0 + 0]);
  o.y = f2bf((v.y - mu) * rstd * gam[e0 + 1] + bet[e0 + 1]);
  o.z = f2bf((v.z - mu) * rstd * gam[e0 + 2] + bet[e0 + 2]);
  o.w = f2bf((v.w - mu) * rstd * gam[e0 + 3] + bet[e0 + 3]);
  ((ushort4*)y)[row * 256 + tid] = o;
}

// ---------------- bf16 GEMM, 256x256 tile, BK=64, 8 waves (2Mx4N), 2-phase dbuf.
// A: (M x K) bf16 row-major. Bt: (N x K) bf16 row-major (weights pre-transposed).
// LDS (u16 units): buf c at c*32768: A [0,16384), B [16384,32768).
//   Tile layout row-major [256 rows][8 slots of 8 bf16]; slot swizzled by row&7.
// EPI 0: out bf16 = acc+bias ; 1: out f32 = acc+bias+res ; 2: out bf16 = gelu(acc+bias)
template <int EPI>
__global__ __launch_bounds__(512, 2) void gemm256(
    const u16* __restrict__ A, const u16* __restrict__ Bt,
    const float* __restrict__ bias, const float* __restrict__ res, void* outp,
    int M, int N, int K) {
  __shared__ u16 lds[65536];  // 128 KiB
  const int tid = threadIdx.x;
  const int w = tid >> 6, lane = tid & 63;
  const int wm = w >> 2, wn = w & 3;
  const int l15 = lane & 15, lk = lane >> 4;

  // T1: bijective XCD-aware swizzle (all launches have nwg % 8 == 0)
  const int gx = (int)gridDim.x;
  const int nwg = gx * (int)gridDim.y;
  const int bid = (int)blockIdx.y * gx + (int)blockIdx.x;
  const int cpx = nwg >> 3;
  const int swz = (bid & 7) * cpx + (bid >> 3);
  const int bx = swz % gx, by = swz / gx;
  const int m0 = by * 256, n0 = bx * 256;

  // Staging geometry: issue i stages rows [i*64, i*64+64); within an issue,
  // wave w covers rows [i*64+w*8, +8); lane L -> row_local L>>3, LDS slot L&7.
  // T2 both-sides: LDS[row][s] holds global slot s^(row&7); so source slot is
  // pre-swizzled here and reads XOR with row&7 below.
  const int srow = w * 8 + (lane >> 3);
  const int sslot = (lane & 7) ^ (srow & 7);
  const u16* aSrc = A + (size_t)(m0 + srow) * K + sslot * 8;
  const u16* bSrc = Bt + (size_t)(n0 + srow) * K + sslot * 8;
  const size_t rstride = (size_t)64 * K;

  f32x4 acc[8][4];
  const f32x4 z = {0.f, 0.f, 0.f, 0.f};
#pragma unroll
  for (int mi = 0; mi < 8; mi++)
#pragma unroll
    for (int ni = 0; ni < 4; ni++) acc[mi][ni] = z;

  auto STAGE = [&](int c, int kt) {
    const u16* ap = aSrc + kt;
    const u16* bp = bSrc + kt;
    u16* lb = lds + c * 32768 + w * 512;   // wave-uniform base
#pragma unroll
    for (int i = 0; i < 4; i++) {
      gload_lds16(ap + i * rstride, lb + i * 4096);
      gload_lds16(bp + i * rstride, lb + 16384 + i * 4096);
    }
  };

  auto COMPUTE = [&](int c) {
    const bf16x8* Ab = (const bf16x8*)(lds + c * 32768);
    const bf16x8* Bb = (const bf16x8*)(lds + c * 32768 + 16384);
#pragma unroll
    for (int ks = 0; ks < 2; ks++) {
      const int sl = (ks * 4 + lk) ^ (l15 & 7);  // T2 read-side swizzle
      bf16x8 af[8], bv[4];
#pragma unroll
      for (int mi = 0; mi < 8; mi++)
        af[mi] = Ab[(wm * 128 + mi * 16 + l15) * 8 + sl];
#pragma unroll
      for (int ni = 0; ni < 4; ni++)
        bv[ni] = Bb[(wn * 64 + ni * 16 + l15) * 8 + sl];
      __builtin_amdgcn_s_setprio(1);
#pragma unroll
      for (int mi = 0; mi < 8; mi++)
#pragma unroll
        for (int ni = 0; ni < 4; ni++)
          acc[mi][ni] = __builtin_amdgcn_mfma_f32_16x16x32_bf16(af[mi], bv[ni],
                                                                acc[mi][ni], 0, 0, 0);
      __builtin_amdgcn_s_setprio(0);
    }
  };

  const int nt = K >> 6;
  STAGE(0, 0);
  __syncthreads();          // vmcnt(0)+barrier: tile 0 resident
  int cur = 0;
  for (int t = 0; t < nt - 1; t++) {
    STAGE(cur ^ 1, (t + 1) << 6);   // issue next tile first (flight hides under MFMA)
    COMPUTE(cur);
    __syncthreads();                // drain stage loads + ds reads; swap
    cur ^= 1;
  }
  COMPUTE(cur);

#pragma unroll
  for (int mi = 0; mi < 8; mi++) {
#pragma unroll
    for (int ni = 0; ni < 4; ni++) {
      int n = n0 + wn * 64 + ni * 16 + l15;       // C/D: col = lane&15
      float bvv = bias[n];
#pragma unroll
      for (int r = 0; r < 4; r++) {
        int m = m0 + wm * 128 + mi * 16 + lk * 4 + r;  // row = (lane>>4)*4 + reg
        size_t idx = (size_t)m * N + n;
        float v = acc[mi][ni][r] + bvv;
        if (EPI == 0) {
          ((u16*)outp)[idx] = f2bf(v);
        } else if (EPI == 1) {
          ((float*)outp)[idx] = v + res[idx];
        } else {
          ((u16*)outp)[idx] = f2bf(gelu_f(v));
        }
      }
    }
  }
}

// ---------------- causal decay mixing as a chunked linear scan.
// S[s] = r*S[s-1] + q[s], r = clip(decay,0.9,1)^(1/4)
// col heads (h<8): q = p,          out = mix_w[h,s]*S + mix_b[h,s]
// row heads (h>=8): q = mix_w[h,t]*p, out = S + mix_b[h,s]
__global__ __launch_bounds__(64) void scan_carry(
    const u16* __restrict__ p, const float* __restrict__ mix_w,
    const float* __restrict__ decay, float* __restrict__ carry) {
  int blk = blockIdx.x;
  int c = blk & 31, h = (blk >> 5) & 15, b = blk >> 9;
  int f = threadIdx.x;
  float d = fminf(fmaxf(decay[h], 0.9f), 1.0f);
  float r = powf(d, 0.25f);
  size_t base = ((size_t)b * TT + c * SC_L) * EE + h * HHD + f;
  const float* mw = mix_w + h * TT + c * SC_L;
  bool isRow = (h >= 8);
  float S = 0.f;
#pragma unroll 4
  for (int t = 0; t < SC_L; t++) {
    float pv = bf2f(p[base + (size_t)t * EE]);
    float q = isRow ? mw[t] * pv : pv;
    S = r * S + q;
  }
  carry[blk * 64 + f] = S;
}

__global__ __launch_bounds__(64) void scan_apply(
    const u16* __restrict__ p, const float* __restrict__ mix_w,
    const float* __restrict__ mix_b, const float* __restrict__ decay,
    const float* __restrict__ carry, u16* __restrict__ mixed) {
  int blk = blockIdx.x;
  int c = blk & 31, h = (blk >> 5) & 15, b = blk >> 9;
  int f = threadIdx.x;
  float d = fminf(fmaxf(decay[h], 0.9f), 1.0f);
  float r = powf(d, 0.25f);
  float rl = powf(r, (float)SC_L);
  int cb = blk - c;
  float S = 0.f;
  for (int cc = 0; cc < c; cc++) S = rl * S + carry[(cb + cc) * 64 + f];
  size_t base = ((size_t)b * TT + c * SC_L) * EE + h * HHD + f;
  const float* mw = mix_w + h * TT + c * SC_L;
  const float* mb = mix_b + h * TT + c * SC_L;
  bool isRow = (h >= 8);
  for (int t = 0; t < SC_L; t++) {
    float pv = bf2f(p[base + (size_t)t * EE]);
    float q = isRow ? mw[t] * pv : pv;
    S = r * S + q;
    float val = (isRow ? S : mw[t] * S) + mb[t];
    mixed[base + (size_t)t * EE] = f2bf(val);
  }
}

extern "C" void kernel_launch(void* const* d_in, const int* in_sizes, int n_in,
                              void* d_out, int out_size, void* d_ws, size_t ws_size,
                              hipStream_t stream) {
  const float* x = (const float*)d_in[0];
  const float* w_proj = (const float*)d_in[1];
  const float* b_proj = (const float*)d_in[2];
  const float* mix_w = (const float*)d_in[3];
  const float* mix_b = (const float*)d_in[4];
  const float* decay = (const float*)d_in[5];
  const float* out_w = (const float*)d_in[6];
  const float* out_b = (const float*)d_in[7];
  const float* ln1_g = (const float*)d_in[8];
  const float* ln1_b = (const float*)d_in[9];
  const float* ln2_g = (const float*)d_in[10];
  const float* ln2_b = (const float*)d_in[11];
  const float* ff_w1 = (const float*)d_in[12];
  const float* ff_b1 = (const float*)d_in[13];
  const float* ff_w2 = (const float*)d_in[14];
  const float* ff_b2 = (const float*)d_in[15];
  float* out = (float*)d_out;

  // ws layout (MiB): [0,2)Wp [2,4)Wo [4,12)W1 [12,20)W2 [20,52)mixed/g
  //                  [52,180)u  (h at 52, p at 84 — both dead before u written)
  //                  [180,181)carry.  Total ~181 MiB.
  char* ws = (char*)d_ws;
  const size_t MiB = 1ull << 20;
  u16* wWp = (u16*)(ws + 0 * MiB);
  u16* wWo = (u16*)(ws + 2 * MiB);
  u16* wW1 = (u16*)(ws + 4 * MiB);
  u16* wW2 = (u16*)(ws + 12 * MiB);
  u16* wMix = (u16*)(ws + 20 * MiB);
  u16* wH = (u16*)(ws + 52 * MiB);
  u16* wP = (u16*)(ws + 84 * MiB);
  u16* wU = (u16*)(ws + 52 * MiB);
  float* wCarry = (float*)(ws + 180 * MiB);

  dim3 tb(32, 8);
  // w_proj (H,E,HD): per-head (E x HD) -> (HD x E), head h at dst row h*64
  transpose_to_bf16<<<dim3(2, 32, 16), tb, 0, stream>>>(w_proj, wWp, 1024, 64,
                                                        65536L, 65536L);
  transpose_to_bf16<<<dim3(32, 32, 1), tb, 0, stream>>>(out_w, wWo, 1024, 1024, 0L, 0L);
  transpose_to_bf16<<<dim3(128, 32, 1), tb, 0, stream>>>(ff_w1, wW1, 1024, 4096, 0L, 0L);
  transpose_to_bf16<<<dim3(32, 128, 1), tb, 0, stream>>>(ff_w2, wW2, 4096, 1024, 0L, 0L);

  ln_to_bf16<<<dim3(MROWS), dim3(256), 0, stream>>>(x, ln1_g, ln1_b, wH);

  gemm256<0><<<dim3(4, 64), dim3(512), 0, stream>>>(
      wH, wWp, b_proj, (const float*)nullptr, (void*)wP, MROWS, 1024, 1024);

  scan_carry<<<dim3(4096), dim3(64), 0, stream>>>(wP, mix_w, decay, wCarry);
  scan_apply<<<dim3(4096), dim3(64), 0, stream>>>(wP, mix_w, mix_b, decay, wCarry, wMix);

  gemm256<1><<<dim3(4, 64), dim3(512), 0, stream>>>(
      wMix, wWo, out_b, x, (void*)out, MROWS, 1024, 1024);

  ln_to_bf16<<<dim3(MROWS), dim3(256), 0, stream>>>(out, ln2_g, ln2_b, wMix);

  gemm256<2><<<dim3(16, 64), dim3(512), 0, stream>>>(
      wMix, wW1, ff_b1, (const float*)nullptr, (void*)wU, MROWS, 4096, 1024);

  gemm256<1><<<dim3(4, 64), dim3(512), 0, stream>>>(
      wU, wW2, ff_b2, out, (void*)out, MROWS, 1024, 4096);
}